// Round 5
// baseline (113.957 us; speedup 1.0000x reference)
//
#include <hip/hip_runtime.h>
#include <stdint.h>

#define B_   32
#define CIN  128
#define HH   56
#define WW   56
#define COUT 256
#define QDIV 7.5f

#define NBLK_AX 2048
#define NBLK_AW 288
#define NBLK_QX (B_ * HH)   // 1792
#define NBLK_QW 288

#define NSLOT 66
#define CSTRIDE (NSLOT * 16)       // 1056 B per ci-chunk
#define ROWB (8 * CSTRIDE)         // 8448 B per image row
#define XS_BYTES (4 * ROWB)        // 33792 B LDS

typedef int v4i  __attribute__((ext_vector_type(4)));
typedef int v16i __attribute__((ext_vector_type(16)));

typedef __attribute__((address_space(3))) unsigned char lds_u8;
typedef __attribute__((address_space(1))) const unsigned char glb_u8;

__device__ __forceinline__ void load_lds16(const void* g, void* l) {
    __builtin_amdgcn_global_load_lds((glb_u8*)g, (lds_u8*)l, 16, 0, 0);
}

// ---------- absmax: blocks [0,2048) -> x, [2048,2336) -> w ----------
__global__ __launch_bounds__(256) void absmax_all_kernel(const float* __restrict__ x,
                                                         const float* __restrict__ w,
                                                         unsigned* __restrict__ mbits) {
    const float* p; int n4, i, stride; unsigned* slot;
    if (blockIdx.x < NBLK_AX) {
        p = x; n4 = B_ * CIN * HH * WW / 4;
        i = blockIdx.x * 256 + threadIdx.x; stride = NBLK_AX * 256; slot = mbits;
    } else {
        p = w; n4 = COUT * CIN * 9 / 4;
        i = (blockIdx.x - NBLK_AX) * 256 + threadIdx.x; stride = NBLK_AW * 256; slot = mbits + 1;
    }
    float m = 0.f;
    for (; i < n4; i += stride) {
        float4 v = ((const float4*)p)[i];
        m = fmaxf(m, fmaxf(fmaxf(fabsf(v.x), fabsf(v.y)),
                           fmaxf(fabsf(v.z), fabsf(v.w))));
    }
    #pragma unroll
    for (int off = 32; off; off >>= 1) m = fmaxf(m, __shfl_down(m, off));
    __shared__ float red[4];
    int lane = threadIdx.x & 63, wv = threadIdx.x >> 6;
    if (lane == 0) red[wv] = m;
    __syncthreads();
    if (threadIdx.x == 0) {
        m = fmaxf(fmaxf(red[0], red[1]), fmaxf(red[2], red[3]));
        atomicMax(slot, __float_as_uint(m));
    }
}

// ---------- quantize: blocks [0,1792) -> x, [1792,2080) -> w ----------
// qx (chunk-major, zero border baked): per (b,h) row of 8448 B:
//   byte addr = c*1056 + s*16 + j   (c: ci-chunk 0..7, s: slot 0..65, j: 0..15)
//   slot s in [1,56] holds pixel w = s-1, ci = c*16+j; slots 0 and 57..65 are zero.
// qw: byte addr = (k*256 + co)*32 + (ci - cc*32), k = (kh*3+kw)*4 + cc
__global__ __launch_bounds__(256) void quant_all_kernel(const float* __restrict__ x,
                                                        const float* __restrict__ w,
                                                        signed char* __restrict__ qx,
                                                        int* __restrict__ qw,
                                                        const unsigned* __restrict__ mbits) {
    if (blockIdx.x < NBLK_QX) {
        __shared__ signed char tile[WW * 132];
        const int bh = blockIdx.x;
        const int b = bh / HH, h = bh % HH;
        const float s = __uint_as_float(mbits[0]) / QDIV;
        const float* src = x + (size_t)b * (CIN * HH * WW) + (size_t)h * WW;
        for (int e = threadIdx.x; e < CIN * WW; e += 256) {
            int ci = e / WW, ww = e - ci * WW;
            float v = src[(size_t)ci * (HH * WW) + ww];
            float q = fminf(fmaxf(rintf(v / s), -8.f), 7.f);
            tile[ww * 132 + ci] = (signed char)q;
        }
        __syncthreads();
        int* dst = (int*)(qx + (size_t)bh * ROWB);
        for (int d = threadIdx.x; d < ROWB / 4; d += 256) {   // 2112 dwords
            int u = d >> 2, dw = d & 3;
            int c = u / NSLOT, s2 = u - c * NSLOT;
            int v = 0;
            if (s2 >= 1 && s2 <= WW)
                v = *(const int*)&tile[(s2 - 1) * 132 + c * 16 + dw * 4];
            dst[d] = v;
        }
    } else {
        int d = (blockIdx.x - NBLK_QX) * 256 + threadIdx.x;  // 73728 dwords
        int dw8 = d & 7;
        int co  = (d >> 3) & 255;
        int cc  = (d >> 11) & 3;
        int t   = d >> 13;
        int kh = t / 3, kw = t % 3;
        float s = __uint_as_float(mbits[1]) / QDIV;
        int pack = 0;
        #pragma unroll
        for (int j = 0; j < 4; ++j) {
            int ci = cc * 32 + dw8 * 4 + j;
            float v = w[(((size_t)co * CIN + ci) * 3 + kh) * 3 + kw];
            float q = fminf(fmaxf(rintf(v / s), -8.f), 7.f);
            pack |= (((int)q) & 0xFF) << (8 * j);
        }
        qw[d] = pack;
    }
}

// ---------- conv: barrier-free i8-MFMA, conflict-free LDS, 128co x 64px waves ----------
// Block: 256 thr / 4 waves; 256 co x 2 rows. Wave (wr=wid&1: co half,
// wc=wid>>1: row) computes 128 co x 64 px -> acc[4][2] (128 AGPR).
// x rows h0-1..h0+2 staged once (linear copy, zero-row substitution at edges);
// weights stream L2->VGPR, two named depth-2 prefetch buffers, no K-loop barriers.
__global__ __launch_bounds__(256, 2) void conv_mfma_kernel(
        const signed char* __restrict__ qx,
        const signed char* __restrict__ qxzero,
        const signed char* __restrict__ qw2,
        const unsigned* __restrict__ mbits,
        const float* __restrict__ bias,
        float* __restrict__ out) {
    __shared__ signed char xs[XS_BYTES];

    // XCD-chunked swizzle (896 % 8 == 0 -> bijective)
    const int sbid = (blockIdx.x & 7) * 112 + (blockIdx.x >> 3);
    const int b  = sbid / 28;
    const int h0 = (sbid % 28) * 2;

    const int tid   = threadIdx.x;
    const int wid   = tid >> 6;
    const int l31   = tid & 31;
    const int lhalf = (tid >> 5) & 1;
    const int wr    = wid & 1;    // co half
    const int wc    = wid >> 1;   // row 0/1

    // ---- stage rows h0-1 .. h0+2 (528 x 16B units per row) ----
    #pragma unroll
    for (int r = 0; r < 4; ++r) {
        const int hy = h0 - 1 + r;
        const signed char* src = (hy >= 0 && hy < HH)
            ? qx + (size_t)(b * HH + hy) * ROWB : qxzero;
        load_lds16(src + tid * 16,        xs + r * ROWB + tid * 16);
        load_lds16(src + 4096 + tid * 16, xs + r * ROWB + 4096 + tid * 16);
        if (tid < 16)
            load_lds16(src + 8192 + tid * 16, xs + r * ROWB + 8192 + tid * 16);
    }
    __syncthreads();

    v16i acc[4][2];
    #pragma unroll
    for (int mi = 0; mi < 4; ++mi)
        #pragma unroll
        for (int ni = 0; ni < 2; ++ni)
            #pragma unroll
            for (int r = 0; r < 16; ++r) acc[mi][ni][r] = 0;

    // A fragment (k, mi): wb + k*8192 + mi*1024
    const signed char* wb = qw2 + wr * 4096 + (l31 * 32 + lhalf * 16);

    v4i a0[4], a1[4];
    #pragma unroll
    for (int mi = 0; mi < 4; ++mi) a0[mi] = *(const v4i*)(wb + mi * 1024);
    #pragma unroll
    for (int mi = 0; mi < 4; ++mi) a1[mi] = *(const v4i*)(wb + 8192 + mi * 1024);

#define CONV_STEP(KV, ABUF, DOPREF)                                                              \
    {                                                                                            \
        const int t_ = (KV) >> 2, cc_ = (KV) & 3;                                                \
        const int kh_ = t_ / 3, kw_ = t_ - kh_ * 3;                                              \
        const signed char* xp_ = xs + (wc + kh_) * ROWB + (cc_ * 2 + lhalf) * CSTRIDE            \
                                 + (l31 + kw_) * 16;                                             \
        const v4i bf0_ = *(const v4i*)xp_;                                                       \
        const v4i bf1_ = *(const v4i*)(xp_ + 512);                                               \
        __builtin_amdgcn_s_setprio(1);                                                           \
        acc[0][0] = __builtin_amdgcn_mfma_i32_32x32x32_i8(ABUF[0], bf0_, acc[0][0], 0, 0, 0);    \
        acc[1][0] = __builtin_amdgcn_mfma_i32_32x32x32_i8(ABUF[1], bf0_, acc[1][0], 0, 0, 0);    \
        acc[2][0] = __builtin_amdgcn_mfma_i32_32x32x32_i8(ABUF[2], bf0_, acc[2][0], 0, 0, 0);    \
        acc[3][0] = __builtin_amdgcn_mfma_i32_32x32x32_i8(ABUF[3], bf0_, acc[3][0], 0, 0, 0);    \
        acc[0][1] = __builtin_amdgcn_mfma_i32_32x32x32_i8(ABUF[0], bf1_, acc[0][1], 0, 0, 0);    \
        acc[1][1] = __builtin_amdgcn_mfma_i32_32x32x32_i8(ABUF[1], bf1_, acc[1][1], 0, 0, 0);    \
        acc[2][1] = __builtin_amdgcn_mfma_i32_32x32x32_i8(ABUF[2], bf1_, acc[2][1], 0, 0, 0);    \
        acc[3][1] = __builtin_amdgcn_mfma_i32_32x32x32_i8(ABUF[3], bf1_, acc[3][1], 0, 0, 0);    \
        __builtin_amdgcn_s_setprio(0);                                                           \
        if (DOPREF) {                                                                            \
            const signed char* ap_ = wb + ((KV) + 2) * 8192;                                     \
            ABUF[0] = *(const v4i*)(ap_);                                                        \
            ABUF[1] = *(const v4i*)(ap_ + 1024);                                                 \
            ABUF[2] = *(const v4i*)(ap_ + 2048);                                                 \
            ABUF[3] = *(const v4i*)(ap_ + 3072);                                                 \
        }                                                                                        \
    }

    #pragma unroll
    for (int kk = 0; kk < 18; ++kk) {
        CONV_STEP(kk * 2,     a0, (kk < 17))
        CONV_STEP(kk * 2 + 1, a1, (kk < 17))
    }
#undef CONV_STEP

    // ---- epilogue: dequant + bias ----
    const float s = (__uint_as_float(mbits[0]) / QDIV) *
                    (__uint_as_float(mbits[1]) / QDIV);
    const int hrow = h0 + wc;
    #pragma unroll
    for (int mi = 0; mi < 4; ++mi) {
        #pragma unroll
        for (int r = 0; r < 16; ++r) {
            const int co = wr * 128 + mi * 32 + (r & 3) + 8 * (r >> 2) + 4 * lhalf;
            const float bv = bias[co];
            float* orow = out + ((size_t)(b * COUT + co) * HH + hrow) * WW;
            orow[l31] = (float)acc[mi][0][r] * s + bv;
            if (l31 < WW - 32) orow[32 + l31] = (float)acc[mi][1][r] * s + bv;
        }
    }
}

extern "C" void kernel_launch(void* const* d_in, const int* in_sizes, int n_in,
                              void* d_out, int out_size, void* d_ws, size_t ws_size,
                              hipStream_t stream) {
    const float* x    = (const float*)d_in[0];
    const float* w    = (const float*)d_in[1];
    const float* bias = (const float*)d_in[2];
    float* out = (float*)d_out;

    unsigned* mbits = (unsigned*)d_ws;
    signed char* qx     = (signed char*)d_ws + 256;
    signed char* qxzero = qx + (size_t)B_ * HH * ROWB;
    signed char* qw2    = qxzero + ROWB;

    hipMemsetAsync(d_ws, 0, 8, stream);
    hipMemsetAsync(qxzero, 0, ROWB, stream);
    hipLaunchKernelGGL(absmax_all_kernel, dim3(NBLK_AX + NBLK_AW), dim3(256), 0, stream,
                       x, w, mbits);
    hipLaunchKernelGGL(quant_all_kernel, dim3(NBLK_QX + NBLK_QW), dim3(256), 0, stream,
                       x, w, qx, (int*)qw2, mbits);
    hipLaunchKernelGGL(conv_mfma_kernel, dim3(B_ * (HH / 2)), dim3(256), 0, stream,
                       qx, qxzero, qw2, mbits, bias, out);
}

// Round 6
// 111.098 us; speedup vs baseline: 1.0257x; 1.0257x over previous
//
#include <hip/hip_runtime.h>
#include <stdint.h>

#define B_   32
#define CIN  128
#define HH   56
#define WW   56
#define COUT 256
#define QDIV 7.5f

#define NBLK_AX 2048
#define NBLK_AW 288
#define NBLK_QX (B_ * HH)   // 1792
#define NBLK_QW 288

#define NSLOT 66
#define CSTRIDE (NSLOT * 16)       // 1056 B per ci-chunk
#define ROWB (8 * CSTRIDE)         // 8448 B per image row
#define XLDS_BYTES (4 * ROWB)      // 33792 B (rows h0-1..h0+2)
#define WCHUNK 8192                // one k-chunk: 256 co x 32 B
#define NWBUF 4
#define LDS_TOTAL (XLDS_BYTES + NWBUF * WCHUNK)   // 66560

typedef int v4i  __attribute__((ext_vector_type(4)));
typedef int v16i __attribute__((ext_vector_type(16)));

typedef __attribute__((address_space(3))) unsigned char lds_u8;
typedef __attribute__((address_space(1))) const unsigned char glb_u8;

__device__ __forceinline__ void load_lds16(const void* g, void* l) {
    __builtin_amdgcn_global_load_lds((glb_u8*)g, (lds_u8*)l, 16, 0, 0);
}

// ---------- absmax: blocks [0,2048) -> x, [2048,2336) -> w ----------
__global__ __launch_bounds__(256) void absmax_all_kernel(const float* __restrict__ x,
                                                         const float* __restrict__ w,
                                                         unsigned* __restrict__ mbits) {
    const float* p; int n4, i, stride; unsigned* slot;
    if (blockIdx.x < NBLK_AX) {
        p = x; n4 = B_ * CIN * HH * WW / 4;
        i = blockIdx.x * 256 + threadIdx.x; stride = NBLK_AX * 256; slot = mbits;
    } else {
        p = w; n4 = COUT * CIN * 9 / 4;
        i = (blockIdx.x - NBLK_AX) * 256 + threadIdx.x; stride = NBLK_AW * 256; slot = mbits + 1;
    }
    float m = 0.f;
    for (; i < n4; i += stride) {
        float4 v = ((const float4*)p)[i];
        m = fmaxf(m, fmaxf(fmaxf(fabsf(v.x), fabsf(v.y)),
                           fmaxf(fabsf(v.z), fabsf(v.w))));
    }
    #pragma unroll
    for (int off = 32; off; off >>= 1) m = fmaxf(m, __shfl_down(m, off));
    __shared__ float red[4];
    int lane = threadIdx.x & 63, wv = threadIdx.x >> 6;
    if (lane == 0) red[wv] = m;
    __syncthreads();
    if (threadIdx.x == 0) {
        m = fmaxf(fmaxf(red[0], red[1]), fmaxf(red[2], red[3]));
        atomicMax(slot, __float_as_uint(m));
    }
}

// ---------- quantize: blocks [0,1792) -> x, [1792,2080) -> w ----------
// qx (chunk-major, zero border baked): per (b,h) row of 8448 B:
//   byte addr = c*1056 + s*16 + j ; slot s in [1,56] = pixel w=s-1, ci = c*16+j
// qw (lane-linear A fragments): chunk k = t*4+cc (t=kh*3+kw); within chunk:
//   byte addr = wrh*4096 + mi*1024 + jh*512 + co31*16 + jl
//   where co = wrh*128 + mi*32 + co31, k-byte j = jh*16 + jl, ci = cc*32 + j
__global__ __launch_bounds__(256) void quant_all_kernel(const float* __restrict__ x,
                                                        const float* __restrict__ w,
                                                        signed char* __restrict__ qx,
                                                        int* __restrict__ qw,
                                                        const unsigned* __restrict__ mbits) {
    if (blockIdx.x < NBLK_QX) {
        __shared__ signed char tile[WW * 132];
        const int bh = blockIdx.x;
        const int b = bh / HH, h = bh % HH;
        const float s = __uint_as_float(mbits[0]) / QDIV;
        const float* src = x + (size_t)b * (CIN * HH * WW) + (size_t)h * WW;
        for (int e = threadIdx.x; e < CIN * WW; e += 256) {
            int ci = e / WW, ww = e - ci * WW;
            float v = src[(size_t)ci * (HH * WW) + ww];
            float q = fminf(fmaxf(rintf(v / s), -8.f), 7.f);
            tile[ww * 132 + ci] = (signed char)q;
        }
        __syncthreads();
        int* dst = (int*)(qx + (size_t)bh * ROWB);
        for (int d = threadIdx.x; d < ROWB / 4; d += 256) {   // 2112 dwords
            int u = d >> 2, dw = d & 3;
            int c = u / NSLOT, s2 = u - c * NSLOT;
            int v = 0;
            if (s2 >= 1 && s2 <= WW)
                v = *(const int*)&tile[(s2 - 1) * 132 + c * 16 + dw * 4];
            dst[d] = v;
        }
    } else {
        int d = (blockIdx.x - NBLK_QX) * 256 + threadIdx.x;  // 73728 dwords
        int k = d >> 11;                  // chunk 0..35
        int u = d & 2047;                 // dword within chunk
        int co = ((u >> 10) & 1) * 128 + ((u >> 8) & 3) * 32 + ((u >> 2) & 31);
        int j0 = ((u >> 7) & 1) * 16 + (u & 3) * 4;   // k-byte 0..28 step 4
        int t = k >> 2, cc = k & 3;
        int kh = t / 3, kw = t - kh * 3;
        float s = __uint_as_float(mbits[1]) / QDIV;
        int pack = 0;
        #pragma unroll
        for (int j = 0; j < 4; ++j) {
            int ci = cc * 32 + j0 + j;
            float v = w[(((size_t)co * CIN + ci) * 3 + kh) * 3 + kw];
            float q = fminf(fmaxf(rintf(v / s), -8.f), 7.f);
            pack |= (((int)q) & 0xFF) << (8 * j);
        }
        qw[d] = pack;
    }
}

// ---------- conv: i8-MFMA, LDS weights w/ counted-vmcnt 4-deep ring ----------
// Block: 256 thr / 4 waves; 256 co x 2 rows. Wave (wr=wid&1, rowidx=wid>>1)
// computes 128 co x 64 px -> acc[4][2]. x staged once; weight chunks (8KB)
// staged 3 iters ahead via global_load_lds; raw s_barrier + s_waitcnt vmcnt(4)
// (never 0 in steady state) per iter.
__global__ __launch_bounds__(256, 2) void conv_mfma_kernel(
        const signed char* __restrict__ qx,
        const signed char* __restrict__ qxzero,
        const signed char* __restrict__ qw2,
        const unsigned* __restrict__ mbits,
        const float* __restrict__ bias,
        float* __restrict__ out) {
    __shared__ signed char lds[LDS_TOTAL];
    signed char* xlds = lds;
    signed char* wlds = lds + XLDS_BYTES;

    // XCD-chunked swizzle (896 % 8 == 0 -> bijective)
    const int sbid = (blockIdx.x & 7) * 112 + (blockIdx.x >> 3);
    const int b  = sbid / 28;
    const int h0 = (sbid % 28) * 2;

    const int tid    = threadIdx.x;
    const int wid    = tid >> 6;
    const int lane   = tid & 63;
    const int l31    = tid & 31;
    const int lhalf  = (tid >> 5) & 1;
    const int wr     = wid & 1;    // co half
    const int rowidx = wid >> 1;   // output row 0/1

    // ---- prologue: stage x rows h0-1..h0+2 + weight chunks 0..2 ----
    #pragma unroll
    for (int r = 0; r < 4; ++r) {
        const int hy = h0 - 1 + r;
        const signed char* src = (hy >= 0 && hy < HH)
            ? qx + (size_t)(b * HH + hy) * ROWB : qxzero;
        load_lds16(src + tid * 16,        xlds + r * ROWB + tid * 16);
        load_lds16(src + 4096 + tid * 16, xlds + r * ROWB + 4096 + tid * 16);
        if (tid < 16)
            load_lds16(src + 8192 + tid * 16, xlds + r * ROWB + 8192 + tid * 16);
    }
    #pragma unroll
    for (int k = 0; k < 3; ++k) {
        load_lds16(qw2 + k * WCHUNK + tid * 16,        wlds + k * WCHUNK + tid * 16);
        load_lds16(qw2 + k * WCHUNK + 4096 + tid * 16, wlds + k * WCHUNK + 4096 + tid * 16);
    }
    __syncthreads();   // full drain once

    v16i acc[4][2];
    #pragma unroll
    for (int mi = 0; mi < 4; ++mi)
        #pragma unroll
        for (int ni = 0; ni < 2; ++ni)
            #pragma unroll
            for (int r = 0; r < 16; ++r) acc[mi][ni][r] = 0;

    #pragma unroll
    for (int i = 0; i < 36; ++i) {
        // stage chunk i+3 into ring slot (i+3)&3 (2 VMEM insts/wave)
        if (i + 3 < 36) {
            const signed char* gs = qw2 + (i + 3) * WCHUNK + tid * 16;
            signed char* ls = wlds + ((i + 3) & 3) * WCHUNK + tid * 16;
            load_lds16(gs, ls);
            load_lds16(gs + 4096, ls + 4096);
        }

        // A fragments: lane-linear, conflict-free
        const signed char* wchunk = wlds + (i & 3) * WCHUNK + wr * 4096 + lane * 16;
        const v4i a0 = *(const v4i*)(wchunk);
        const v4i a1 = *(const v4i*)(wchunk + 1024);
        const v4i a2 = *(const v4i*)(wchunk + 2048);
        const v4i a3 = *(const v4i*)(wchunk + 3072);

        // B fragments
        const int t = i >> 2, cc = i & 3;
        const int kh = t / 3, kw = t - kh * 3;
        const signed char* xp = xlds + (rowidx + kh) * ROWB
                                + (cc * 2 + lhalf) * CSTRIDE + (l31 + kw) * 16;
        const v4i b0 = *(const v4i*)xp;
        const v4i b1 = *(const v4i*)(xp + 512);

        __builtin_amdgcn_s_setprio(1);
        acc[0][0] = __builtin_amdgcn_mfma_i32_32x32x32_i8(a0, b0, acc[0][0], 0, 0, 0);
        acc[1][0] = __builtin_amdgcn_mfma_i32_32x32x32_i8(a1, b0, acc[1][0], 0, 0, 0);
        acc[2][0] = __builtin_amdgcn_mfma_i32_32x32x32_i8(a2, b0, acc[2][0], 0, 0, 0);
        acc[3][0] = __builtin_amdgcn_mfma_i32_32x32x32_i8(a3, b0, acc[3][0], 0, 0, 0);
        acc[0][1] = __builtin_amdgcn_mfma_i32_32x32x32_i8(a0, b1, acc[0][1], 0, 0, 0);
        acc[1][1] = __builtin_amdgcn_mfma_i32_32x32x32_i8(a1, b1, acc[1][1], 0, 0, 0);
        acc[2][1] = __builtin_amdgcn_mfma_i32_32x32x32_i8(a2, b1, acc[2][1], 0, 0, 0);
        acc[3][1] = __builtin_amdgcn_mfma_i32_32x32x32_i8(a3, b1, acc[3][1], 0, 0, 0);
        __builtin_amdgcn_s_setprio(0);

        // counted vmcnt: wait until stage(i+1) complete, keep i+2/i+3 in flight
        if (i <= 32)      { asm volatile("s_waitcnt vmcnt(4)" ::: "memory"); }
        else if (i == 33) { asm volatile("s_waitcnt vmcnt(2)" ::: "memory"); }
        else if (i == 34) { asm volatile("s_waitcnt vmcnt(0)" ::: "memory"); }
        if (i < 35) {
            __builtin_amdgcn_s_barrier();
            __builtin_amdgcn_sched_barrier(0);
        }
    }

    // ---- epilogue: dequant + bias ----
    const float s = (__uint_as_float(mbits[0]) / QDIV) *
                    (__uint_as_float(mbits[1]) / QDIV);
    const int hrow = h0 + rowidx;
    #pragma unroll
    for (int mi = 0; mi < 4; ++mi) {
        #pragma unroll
        for (int r = 0; r < 16; ++r) {
            const int co = wr * 128 + mi * 32 + (r & 3) + 8 * (r >> 2) + 4 * lhalf;
            const float bv = bias[co];
            float* orow = out + ((size_t)(b * COUT + co) * HH + hrow) * WW;
            orow[l31] = (float)acc[mi][0][r] * s + bv;
            if (l31 < WW - 32) orow[32 + l31] = (float)acc[mi][1][r] * s + bv;
        }
    }
}

extern "C" void kernel_launch(void* const* d_in, const int* in_sizes, int n_in,
                              void* d_out, int out_size, void* d_ws, size_t ws_size,
                              hipStream_t stream) {
    const float* x    = (const float*)d_in[0];
    const float* w    = (const float*)d_in[1];
    const float* bias = (const float*)d_in[2];
    float* out = (float*)d_out;

    unsigned* mbits = (unsigned*)d_ws;
    signed char* qx     = (signed char*)d_ws + 256;
    signed char* qxzero = qx + (size_t)B_ * HH * ROWB;
    signed char* qw2    = qxzero + ROWB;

    hipMemsetAsync(d_ws, 0, 8, stream);
    hipMemsetAsync(qxzero, 0, ROWB, stream);
    hipLaunchKernelGGL(absmax_all_kernel, dim3(NBLK_AX + NBLK_AW), dim3(256), 0, stream,
                       x, w, mbits);
    hipLaunchKernelGGL(quant_all_kernel, dim3(NBLK_QX + NBLK_QW), dim3(256), 0, stream,
                       x, w, qx, (int*)qw2, mbits);
    hipLaunchKernelGGL(conv_mfma_kernel, dim3(B_ * (HH / 2)), dim3(256), 0, stream,
                       qx, qxzero, qw2, mbits, bias, out);
}